// Round 5
// baseline (54.491 us; speedup 1.0000x reference)
//
#include <hip/hip_runtime.h>

constexpr int NPIX  = 1 << 20;   // 1024*1024 pixels
constexpr int NCLS  = 21;
constexpr int NBINS = 4096;      // linear bins over [0,16): width = 3.91e-3
constexpr float RANGE = 16.0f;
constexpr float BIN_SCALE = NBINS / RANGE;

typedef int   iv4 __attribute__((ext_vector_type(4)));   // native vecs: OK for
typedef float fv4 __attribute__((ext_vector_type(4)));   // __builtin_nontemporal_load

// ---------------------------------------------------------------------------
// 1) per-pixel argmax over classes (first occurrence of max, like jnp.argmax)
//    int4-vectorized; result packed to uchar (1 MB -> L2-resident re-reads)
// ---------------------------------------------------------------------------
__global__ void k_argmax(const iv4* __restrict__ label, uchar4* __restrict__ lbl) {
    int i = blockIdx.x * blockDim.x + threadIdx.x;     // over NPIX/4
    if (i >= NPIX / 4) return;
    iv4 best = __builtin_nontemporal_load(&label[i]);
    int bx = 0, by = 0, bz = 0, bw = 0;
    #pragma unroll
    for (int c = 1; c < NCLS; ++c) {
        iv4 v = __builtin_nontemporal_load(&label[(size_t)c * (NPIX / 4) + i]);
        if (v.x > best.x) { best.x = v.x; bx = c; }    // strict > keeps FIRST max
        if (v.y > best.y) { best.y = v.y; by = c; }
        if (v.z > best.z) { best.z = v.z; bz = c; }
        if (v.w > best.w) { best.w = v.w; bw = c; }
    }
    lbl[i] = make_uchar4((unsigned char)bx, (unsigned char)by,
                         (unsigned char)bz, (unsigned char)bw);
}

// ---------------------------------------------------------------------------
// 2) per-(class,chunk) LDS-private histogram; u32 packs (n | n_fg<<16).
//    chunkPix = 32768 so both fields fit u16. Flush = coalesced uint4 stores.
// ---------------------------------------------------------------------------
__global__ void __launch_bounds__(512)
k_hist(const fv4* __restrict__ pred4, const uchar4* __restrict__ lbl4,
       unsigned int* __restrict__ part, int nchunk) {
    __shared__ unsigned int sh[NBINS];                 // 16 KB
    const int chunk = blockIdx.x;
    const int c     = blockIdx.y;
    const int t     = threadIdx.x;
    const int chunkPix = NPIX / nchunk;

    for (int b = t; b < NBINS; b += 512) sh[b] = 0u;
    __syncthreads();

    const size_t pbase4 = ((size_t)c * NPIX + (size_t)chunk * chunkPix) / 4;
    const size_t lbase4 = ((size_t)chunk * chunkPix) / 4;
    const int n4 = chunkPix / 4;

    for (int k = t; k < n4; k += 512) {
        fv4 p = __builtin_nontemporal_load(&pred4[pbase4 + k]);
        uchar4 l = lbl4[lbase4 + k];
        {
            unsigned int fg = (l.x == c) ? 1u : 0u;
            float e = fabsf((float)fg - p.x);
            int bin = (int)(e * BIN_SCALE); bin = bin < NBINS - 1 ? bin : NBINS - 1;
            atomicAdd(&sh[bin], 1u | (fg << 16));
        }
        {
            unsigned int fg = (l.y == c) ? 1u : 0u;
            float e = fabsf((float)fg - p.y);
            int bin = (int)(e * BIN_SCALE); bin = bin < NBINS - 1 ? bin : NBINS - 1;
            atomicAdd(&sh[bin], 1u | (fg << 16));
        }
        {
            unsigned int fg = (l.z == c) ? 1u : 0u;
            float e = fabsf((float)fg - p.z);
            int bin = (int)(e * BIN_SCALE); bin = bin < NBINS - 1 ? bin : NBINS - 1;
            atomicAdd(&sh[bin], 1u | (fg << 16));
        }
        {
            unsigned int fg = (l.w == c) ? 1u : 0u;
            float e = fabsf((float)fg - p.w);
            int bin = (int)(e * BIN_SCALE); bin = bin < NBINS - 1 ? bin : NBINS - 1;
            atomicAdd(&sh[bin], 1u | (fg << 16));
        }
    }
    __syncthreads();

    uint4* dst = (uint4*)(part + ((size_t)c * nchunk + chunk) * NBINS);
    const uint4* src = (const uint4*)sh;
    for (int b = t; b < NBINS / 4; b += 512) dst[b] = src[b];   // coalesced 16B
}

// ---------------------------------------------------------------------------
// 3) merge chunk partials -> per-class u64 hist (n | n_fg<<32), coalesced
// ---------------------------------------------------------------------------
__global__ void k_merge(const unsigned int* __restrict__ part,
                        unsigned long long* __restrict__ hist, int nchunk) {
    int b = blockIdx.x * blockDim.x + threadIdx.x;     // over NCLS*NBINS
    if (b >= NCLS * NBINS) return;
    int c = b / NBINS, bin = b % NBINS;
    unsigned int n = 0, f = 0;
    for (int k = 0; k < nchunk; ++k) {
        unsigned int v = part[((size_t)c * nchunk + k) * NBINS + bin];
        n += v & 0xFFFFu;
        f += v >> 16;
    }
    hist[b] = (unsigned long long)n | ((unsigned long long)f << 32);
}

// ---------------------------------------------------------------------------
// 4) per-class descending scan over bins; Lovasz loss via j = i/(G+i-F)
//    shuffle-based block scan: 2 barriers total (vs 20 for Hillis-Steele)
// ---------------------------------------------------------------------------
__global__ void __launch_bounds__(1024)
k_scan(const unsigned long long* __restrict__ hist, double* __restrict__ losses) {
    const int c    = blockIdx.x;
    const int t    = threadIdx.x;
    const int lane = t & 63;
    const int wv   = t >> 6;                           // 16 waves
    const unsigned long long* h = hist + (size_t)c * NBINS;
    constexpr int BPT = NBINS / 1024;                  // 4 bins per thread

    unsigned long long hv[BPT];
    unsigned int tn = 0, tf = 0;
    #pragma unroll
    for (int k = 0; k < BPT; ++k) {
        hv[k] = h[NBINS - 1 - (t * BPT + k)];          // descending rank order
        tn += (unsigned int)hv[k];
        tf += (unsigned int)(hv[k] >> 32);
    }

    // wave-inclusive scan of (tn, tf)
    unsigned int in_ = tn, if_ = tf;
    #pragma unroll
    for (int off = 1; off < 64; off <<= 1) {
        unsigned int an = __shfl_up(in_, off, 64);
        unsigned int af = __shfl_up(if_, off, 64);
        if (lane >= off) { in_ += an; if_ += af; }
    }

    __shared__ unsigned int swn[16], swf[16];
    if (lane == 63) { swn[wv] = in_; swf[wv] = if_; }
    __syncthreads();

    if (wv == 0 && lane < 16) {                        // scan the 16 wave totals
        unsigned int a = swn[lane], b = swf[lane];
        #pragma unroll
        for (int off = 1; off < 16; off <<= 1) {
            unsigned int an = __shfl_up(a, off, 64);
            unsigned int af = __shfl_up(b, off, 64);
            if (lane >= off) { a += an; b += af; }
        }
        swn[lane] = a; swf[lane] = b;                  // inclusive wave prefixes
    }
    __syncthreads();

    const unsigned int G = swf[15];                    // total foreground count
    unsigned int i = in_ - tn + (wv ? swn[wv - 1] : 0u);   // exclusive prefix
    unsigned int F = if_ - tf + (wv ? swf[wv - 1] : 0u);

    double jprev = (i > 0) ? (double)i / (double)(G + i - F) : 0.0;
    double acc = 0.0;
    #pragma unroll
    for (int k = 0; k < BPT; ++k) {
        unsigned int n = (unsigned int)hv[k];
        if (n) {
            unsigned int nf = (unsigned int)(hv[k] >> 32);
            i += n; F += nf;
            double jhi = (double)i / (double)(G + i - F);
            int bin = NBINS - 1 - (t * BPT + k);
            acc += ((bin + 0.5) * (double)(RANGE / NBINS)) * (jhi - jprev);
            jprev = jhi;
        }
    }

    // block reduce: wave shfl reduce, then one wave over 16 partials
    #pragma unroll
    for (int off = 32; off > 0; off >>= 1) acc += __shfl_down(acc, off, 64);
    __shared__ double sd[16];
    if (lane == 0) sd[wv] = acc;
    __syncthreads();
    if (t == 0) {
        double s = 0.0;
        #pragma unroll
        for (int k = 0; k < 16; ++k) s += sd[k];
        losses[c] = s;
    }
}

// ---------------------------------------------------------------------------
// 5) mean over classes
// ---------------------------------------------------------------------------
__global__ void k_final(const double* __restrict__ losses, float* __restrict__ out) {
    if (threadIdx.x == 0 && blockIdx.x == 0) {
        double s = 0.0;
        for (int c = 0; c < NCLS; ++c) s += losses[c];
        out[0] = (float)(s / NCLS);
    }
}

extern "C" void kernel_launch(void* const* d_in, const int* in_sizes, int n_in,
                              void* d_out, int out_size, void* d_ws, size_t ws_size,
                              hipStream_t stream) {
    const float* pred  = (const float*)d_in[0];
    const int*   label = (const int*)d_in[1];
    float* out = (float*)d_out;

    // pick nchunk to fit workspace: lbl(uchar) + part + hist + losses
    int nchunk = 32;
    auto need = [](int nc) {
        return (size_t)NPIX
             + (size_t)NCLS * nc * NBINS * 4
             + (size_t)NCLS * NBINS * 8
             + (size_t)NCLS * 8;
    };
    while (nchunk > 1 && need(nchunk) > ws_size) nchunk >>= 1;

    char* ws = (char*)d_ws;
    unsigned char* lbl = (unsigned char*)ws;
    size_t off = (size_t)NPIX;
    unsigned int* part = (unsigned int*)(ws + off);
    off += (size_t)NCLS * nchunk * NBINS * 4;
    unsigned long long* hist = (unsigned long long*)(ws + off);
    off += (size_t)NCLS * NBINS * 8;
    double* losses = (double*)(ws + off);

    k_argmax<<<NPIX / 4 / 256, 256, 0, stream>>>((const iv4*)label, (uchar4*)lbl);
    dim3 hgrid(nchunk, NCLS);
    k_hist<<<hgrid, 512, 0, stream>>>((const fv4*)pred, (const uchar4*)lbl,
                                      part, nchunk);
    k_merge<<<(NCLS * NBINS + 255) / 256, 256, 0, stream>>>(part, hist, nchunk);
    k_scan<<<NCLS, 1024, 0, stream>>>(hist, losses);
    k_final<<<1, 64, 0, stream>>>(losses, out);
}

// Round 6
// 53.043 us; speedup vs baseline: 1.0273x; 1.0273x over previous
//
#include <hip/hip_runtime.h>

constexpr int NPIX  = 1 << 20;      // 1024*1024 pixels
constexpr int NCLS  = 21;
constexpr int NBINS = 960;          // linear bins over [0,8): width = 8.33e-3
constexpr float RANGE = 8.0f;
constexpr float BIN_SCALE = NBINS / RANGE;   // 120
constexpr int NCHUNK = 256;
constexpr int CHUNK_PIX = NPIX / NCHUNK;     // 4096 (fits u16 bin counts)

typedef int   iv4 __attribute__((ext_vector_type(4)));
typedef float fv4 __attribute__((ext_vector_type(4)));

// ---------------------------------------------------------------------------
// 1) FUSED: per-pixel argmax over classes + 21 LDS-private class histograms.
//    LDS = 21*960*4 = 78.75 KB -> 2 blocks/CU (157.5 KB of 160 KB), 32 waves.
//    u32 bin packs (n | n_fg<<16); chunk = 4096 pixels so both fit u16.
//    Flush = coalesced uint4 stores (NO global atomics).
// ---------------------------------------------------------------------------
__global__ void __launch_bounds__(1024, 8)
k_fused(const iv4* __restrict__ label4, const fv4* __restrict__ pred4,
        unsigned int* __restrict__ part) {
    __shared__ unsigned int sh[NCLS * NBINS];
    const int chunk = blockIdx.x;
    const int t     = threadIdx.x;

    for (int b = t; b < NCLS * NBINS; b += 1024) sh[b] = 0u;
    __syncthreads();

    const int q = chunk * (CHUNK_PIX / 4) + t;   // this thread's pixel-quad

    // ---- argmax over classes (strict > keeps FIRST max, like jnp.argmax)
    iv4 best = label4[q];
    int bx = 0, by = 0, bz = 0, bw = 0;
    for (int c = 1; c < NCLS; ++c) {
        iv4 v = label4[(size_t)c * (NPIX / 4) + q];
        if (v.x > best.x) { best.x = v.x; bx = c; }
        if (v.y > best.y) { best.y = v.y; by = c; }
        if (v.z > best.z) { best.z = v.z; bz = c; }
        if (v.w > best.w) { best.w = v.w; bw = c; }
    }

    // ---- histogram all 21 classes for these 4 pixels
    for (int c = 0; c < NCLS; ++c) {
        fv4 p = pred4[(size_t)c * (NPIX / 4) + q];
        unsigned int* shc = sh + c * NBINS;
        {
            unsigned int fg = (bx == c) ? 1u : 0u;
            float e = fabsf((float)fg - p.x);
            int bin = (int)(e * BIN_SCALE); bin = bin < NBINS - 1 ? bin : NBINS - 1;
            atomicAdd(&shc[bin], 1u | (fg << 16));
        }
        {
            unsigned int fg = (by == c) ? 1u : 0u;
            float e = fabsf((float)fg - p.y);
            int bin = (int)(e * BIN_SCALE); bin = bin < NBINS - 1 ? bin : NBINS - 1;
            atomicAdd(&shc[bin], 1u | (fg << 16));
        }
        {
            unsigned int fg = (bz == c) ? 1u : 0u;
            float e = fabsf((float)fg - p.z);
            int bin = (int)(e * BIN_SCALE); bin = bin < NBINS - 1 ? bin : NBINS - 1;
            atomicAdd(&shc[bin], 1u | (fg << 16));
        }
        {
            unsigned int fg = (bw == c) ? 1u : 0u;
            float e = fabsf((float)fg - p.w);
            int bin = (int)(e * BIN_SCALE); bin = bin < NBINS - 1 ? bin : NBINS - 1;
            atomicAdd(&shc[bin], 1u | (fg << 16));
        }
    }
    __syncthreads();

    // ---- flush: block-contiguous, coalesced 16B stores
    uint4* dst = (uint4*)(part + (size_t)chunk * NCLS * NBINS);
    const uint4* src = (const uint4*)sh;
    for (int b = t; b < NCLS * NBINS / 4; b += 1024) dst[b] = src[b];
}

// ---------------------------------------------------------------------------
// 2) merge chunk partials -> per-class u64 hist (n | n_fg<<32), coalesced
// ---------------------------------------------------------------------------
__global__ void k_merge(const unsigned int* __restrict__ part,
                        unsigned long long* __restrict__ hist) {
    int b = blockIdx.x * blockDim.x + threadIdx.x;     // over NCLS*NBINS
    if (b >= NCLS * NBINS) return;
    unsigned int n = 0, f = 0;
    for (int k = 0; k < NCHUNK; ++k) {
        unsigned int v = part[(size_t)k * NCLS * NBINS + b];
        n += v & 0xFFFFu;
        f += v >> 16;
    }
    hist[b] = (unsigned long long)n | ((unsigned long long)f << 32);
}

// ---------------------------------------------------------------------------
// 3) per-class descending scan over bins; Lovasz loss via j = i/(G+i-F)
//    1 bin/thread, shuffle-based block scan (2 barriers)
// ---------------------------------------------------------------------------
__global__ void __launch_bounds__(1024)
k_scan(const unsigned long long* __restrict__ hist, double* __restrict__ losses) {
    const int c    = blockIdx.x;
    const int t    = threadIdx.x;
    const int lane = t & 63;
    const int wv   = t >> 6;                           // 16 waves
    const unsigned long long* h = hist + (size_t)c * NBINS;

    // rank t: 0 = largest-error bin. Threads >= NBINS are zero-padding.
    const int bin = NBINS - 1 - t;                     // valid when t < NBINS
    unsigned long long hv = (t < NBINS) ? h[bin] : 0ULL;
    unsigned int tn = (unsigned int)hv;
    unsigned int tf = (unsigned int)(hv >> 32);

    // wave-inclusive scan of (tn, tf)
    unsigned int in_ = tn, if_ = tf;
    #pragma unroll
    for (int off = 1; off < 64; off <<= 1) {
        unsigned int an = __shfl_up(in_, off, 64);
        unsigned int af = __shfl_up(if_, off, 64);
        if (lane >= off) { in_ += an; if_ += af; }
    }

    __shared__ unsigned int swn[16], swf[16];
    if (lane == 63) { swn[wv] = in_; swf[wv] = if_; }
    __syncthreads();

    if (wv == 0 && lane < 16) {                        // scan the 16 wave totals
        unsigned int a = swn[lane], b = swf[lane];
        #pragma unroll
        for (int off = 1; off < 16; off <<= 1) {
            unsigned int an = __shfl_up(a, off, 64);
            unsigned int af = __shfl_up(b, off, 64);
            if (lane >= off) { a += an; b += af; }
        }
        swn[lane] = a; swf[lane] = b;                  // inclusive wave prefixes
    }
    __syncthreads();

    const unsigned int G = swf[15];                    // total foreground count
    unsigned int i = in_ - tn + (wv ? swn[wv - 1] : 0u);   // exclusive prefix
    unsigned int F = if_ - tf + (wv ? swf[wv - 1] : 0u);

    double acc = 0.0;
    if (tn) {
        double jprev = (i > 0) ? (double)i / (double)(G + i - F) : 0.0;
        unsigned int i2 = i + tn, F2 = F + tf;
        double jhi = (double)i2 / (double)(G + i2 - F2);
        acc = ((bin + 0.5) * (double)(RANGE / NBINS)) * (jhi - jprev);
    }

    // block reduce: wave shfl reduce, then one thread over 16 partials
    #pragma unroll
    for (int off = 32; off > 0; off >>= 1) acc += __shfl_down(acc, off, 64);
    __shared__ double sd[16];
    if (lane == 0) sd[wv] = acc;
    __syncthreads();
    if (t == 0) {
        double s = 0.0;
        #pragma unroll
        for (int k = 0; k < 16; ++k) s += sd[k];
        losses[c] = s;
    }
}

// ---------------------------------------------------------------------------
// 4) mean over classes
// ---------------------------------------------------------------------------
__global__ void k_final(const double* __restrict__ losses, float* __restrict__ out) {
    if (threadIdx.x == 0 && blockIdx.x == 0) {
        double s = 0.0;
        for (int c = 0; c < NCLS; ++c) s += losses[c];
        out[0] = (float)(s / NCLS);
    }
}

extern "C" void kernel_launch(void* const* d_in, const int* in_sizes, int n_in,
                              void* d_out, int out_size, void* d_ws, size_t ws_size,
                              hipStream_t stream) {
    const float* pred  = (const float*)d_in[0];
    const int*   label = (const int*)d_in[1];
    float* out = (float*)d_out;

    char* ws = (char*)d_ws;
    unsigned int* part = (unsigned int*)ws;                    // 20.6 MB
    size_t off = (size_t)NCHUNK * NCLS * NBINS * 4;
    unsigned long long* hist = (unsigned long long*)(ws + off); // 158 KB
    off += (size_t)NCLS * NBINS * 8;
    double* losses = (double*)(ws + off);                      // 168 B

    k_fused<<<NCHUNK, 1024, 0, stream>>>((const iv4*)label, (const fv4*)pred, part);
    k_merge<<<(NCLS * NBINS + 255) / 256, 256, 0, stream>>>(part, hist);
    k_scan<<<NCLS, 1024, 0, stream>>>(hist, losses);
    k_final<<<1, 64, 0, stream>>>(losses, out);
}

// Round 7
// 45.245 us; speedup vs baseline: 1.2044x; 1.1723x over previous
//
#include <hip/hip_runtime.h>

constexpr int NPIX  = 1 << 20;      // 1024*1024 pixels
constexpr int NCLS  = 21;
constexpr int NBINS = 960;          // linear bins over [0,8): width = 8.33e-3
constexpr float RANGE = 8.0f;
constexpr float BIN_SCALE = NBINS / RANGE;   // 120
constexpr int NCHUNK = 256;
constexpr int CHUNK_PIX = NPIX / NCHUNK;     // 4096 pixels = 1024 quads
constexpr int NGRP = 8;                      // merge hierarchy
constexpr int CPG  = NCHUNK / NGRP;          // 32 chunks per group

typedef int   iv4 __attribute__((ext_vector_type(4)));
typedef float fv4 __attribute__((ext_vector_type(4)));

// ---------------------------------------------------------------------------
// 1) FUSED argmax + 21-class LDS histograms, with REGISTER-STAGED loads:
//    all 21 label quads issued back-to-back (21 KB in flight per wave),
//    then all 21 pred quads. VGPR target ~100 (__launch_bounds__(1024,4)).
// ---------------------------------------------------------------------------
__global__ void __launch_bounds__(1024, 4)
k_fused(const iv4* __restrict__ label4, const fv4* __restrict__ pred4,
        unsigned int* __restrict__ part) {
    __shared__ unsigned int sh[NCLS * NBINS];          // 78.75 KB
    const int chunk = blockIdx.x;
    const int t     = threadIdx.x;

    {   // zero LDS (vectorized)
        uint4* s4 = (uint4*)sh;
        for (int b = t; b < NCLS * NBINS / 4; b += 1024)
            s4[b] = make_uint4(0u, 0u, 0u, 0u);
    }
    __syncthreads();

    const int q = chunk * (CHUNK_PIX / 4) + t;         // this thread's quad

    // ---- stage all 21 label loads (independent, all in flight)
    iv4 lv[NCLS];
    #pragma unroll
    for (int c = 0; c < NCLS; ++c)
        lv[c] = label4[(size_t)c * (NPIX / 4) + q];

    // ---- register-only argmax (strict > keeps FIRST max, like jnp.argmax)
    int bx = 0, by = 0, bz = 0, bw = 0;
    iv4 best = lv[0];
    #pragma unroll
    for (int c = 1; c < NCLS; ++c) {
        if (lv[c].x > best.x) { best.x = lv[c].x; bx = c; }
        if (lv[c].y > best.y) { best.y = lv[c].y; by = c; }
        if (lv[c].z > best.z) { best.z = lv[c].z; bz = c; }
        if (lv[c].w > best.w) { best.w = lv[c].w; bw = c; }
    }

    // ---- stage all 21 pred loads (independent, all in flight)
    fv4 pv[NCLS];
    #pragma unroll
    for (int c = 0; c < NCLS; ++c)
        pv[c] = pred4[(size_t)c * (NPIX / 4) + q];

    // ---- histogram: u32 bin packs (n | n_fg<<16); chunk=4096 pix fits u16
    #pragma unroll
    for (int c = 0; c < NCLS; ++c) {
        unsigned int* shc = sh + c * NBINS;
        {
            unsigned int fg = (bx == c) ? 1u : 0u;
            float e = fabsf((float)fg - pv[c].x);
            int bin = (int)(e * BIN_SCALE); bin = bin < NBINS - 1 ? bin : NBINS - 1;
            atomicAdd(&shc[bin], 1u | (fg << 16));
        }
        {
            unsigned int fg = (by == c) ? 1u : 0u;
            float e = fabsf((float)fg - pv[c].y);
            int bin = (int)(e * BIN_SCALE); bin = bin < NBINS - 1 ? bin : NBINS - 1;
            atomicAdd(&shc[bin], 1u | (fg << 16));
        }
        {
            unsigned int fg = (bz == c) ? 1u : 0u;
            float e = fabsf((float)fg - pv[c].z);
            int bin = (int)(e * BIN_SCALE); bin = bin < NBINS - 1 ? bin : NBINS - 1;
            atomicAdd(&shc[bin], 1u | (fg << 16));
        }
        {
            unsigned int fg = (bw == c) ? 1u : 0u;
            float e = fabsf((float)fg - pv[c].w);
            int bin = (int)(e * BIN_SCALE); bin = bin < NBINS - 1 ? bin : NBINS - 1;
            atomicAdd(&shc[bin], 1u | (fg << 16));
        }
    }
    __syncthreads();

    // ---- flush: block-contiguous, coalesced 16B stores
    uint4* dst = (uint4*)(part + (size_t)chunk * NCLS * NBINS);
    const uint4* src = (const uint4*)sh;
    for (int b = t; b < NCLS * NBINS / 4; b += 1024) dst[b] = src[b];
}

// ---------------------------------------------------------------------------
// 2) hierarchical merge: each (bin-block, group) sums 32 chunks -> u64 part2
// ---------------------------------------------------------------------------
__global__ void k_merge(const unsigned int* __restrict__ part,
                        unsigned long long* __restrict__ part2) {
    int b = blockIdx.x * blockDim.x + threadIdx.x;     // over NCLS*NBINS
    if (b >= NCLS * NBINS) return;
    int g = blockIdx.y;
    unsigned int n = 0, f = 0;
    for (int k = 0; k < CPG; ++k) {
        unsigned int v = part[(size_t)(g * CPG + k) * (NCLS * NBINS) + b];
        n += v & 0xFFFFu;
        f += v >> 16;
    }
    part2[(size_t)g * (NCLS * NBINS) + b] =
        (unsigned long long)n | ((unsigned long long)f << 32);
}

// ---------------------------------------------------------------------------
// 3) per-class descending scan over bins; Lovasz loss via j = i/(G+i-F)
//    sums the 8 group partials inline; shuffle-based block scan
// ---------------------------------------------------------------------------
__global__ void __launch_bounds__(1024)
k_scan(const unsigned long long* __restrict__ part2, double* __restrict__ losses) {
    const int c    = blockIdx.x;
    const int t    = threadIdx.x;
    const int lane = t & 63;
    const int wv   = t >> 6;                           // 16 waves

    // rank t: 0 = largest-error bin. Threads >= NBINS are zero-padding.
    const int bin = NBINS - 1 - t;
    unsigned int tn = 0, tf = 0;
    if (t < NBINS) {
        #pragma unroll
        for (int g = 0; g < NGRP; ++g) {
            unsigned long long v =
                part2[(size_t)g * (NCLS * NBINS) + (size_t)c * NBINS + bin];
            tn += (unsigned int)v;
            tf += (unsigned int)(v >> 32);
        }
    }

    // wave-inclusive scan of (tn, tf)
    unsigned int in_ = tn, if_ = tf;
    #pragma unroll
    for (int off = 1; off < 64; off <<= 1) {
        unsigned int an = __shfl_up(in_, off, 64);
        unsigned int af = __shfl_up(if_, off, 64);
        if (lane >= off) { in_ += an; if_ += af; }
    }

    __shared__ unsigned int swn[16], swf[16];
    if (lane == 63) { swn[wv] = in_; swf[wv] = if_; }
    __syncthreads();

    if (wv == 0 && lane < 16) {                        // scan the 16 wave totals
        unsigned int a = swn[lane], b = swf[lane];
        #pragma unroll
        for (int off = 1; off < 16; off <<= 1) {
            unsigned int an = __shfl_up(a, off, 64);
            unsigned int af = __shfl_up(b, off, 64);
            if (lane >= off) { a += an; b += af; }
        }
        swn[lane] = a; swf[lane] = b;                  // inclusive wave prefixes
    }
    __syncthreads();

    const unsigned int G = swf[15];                    // total foreground count
    unsigned int i = in_ - tn + (wv ? swn[wv - 1] : 0u);   // exclusive prefix
    unsigned int F = if_ - tf + (wv ? swf[wv - 1] : 0u);

    double acc = 0.0;
    if (tn) {
        double jprev = (i > 0) ? (double)i / (double)(G + i - F) : 0.0;
        unsigned int i2 = i + tn, F2 = F + tf;
        double jhi = (double)i2 / (double)(G + i2 - F2);
        acc = ((bin + 0.5) * (double)(RANGE / NBINS)) * (jhi - jprev);
    }

    // block reduce: wave shfl reduce, then one thread over 16 partials
    #pragma unroll
    for (int off = 32; off > 0; off >>= 1) acc += __shfl_down(acc, off, 64);
    __shared__ double sd[16];
    if (lane == 0) sd[wv] = acc;
    __syncthreads();
    if (t == 0) {
        double s = 0.0;
        #pragma unroll
        for (int k = 0; k < 16; ++k) s += sd[k];
        losses[c] = s;
    }
}

// ---------------------------------------------------------------------------
// 4) mean over classes
// ---------------------------------------------------------------------------
__global__ void k_final(const double* __restrict__ losses, float* __restrict__ out) {
    if (threadIdx.x == 0 && blockIdx.x == 0) {
        double s = 0.0;
        for (int c = 0; c < NCLS; ++c) s += losses[c];
        out[0] = (float)(s / NCLS);
    }
}

extern "C" void kernel_launch(void* const* d_in, const int* in_sizes, int n_in,
                              void* d_out, int out_size, void* d_ws, size_t ws_size,
                              hipStream_t stream) {
    const float* pred  = (const float*)d_in[0];
    const int*   label = (const int*)d_in[1];
    float* out = (float*)d_out;

    char* ws = (char*)d_ws;
    unsigned int* part = (unsigned int*)ws;                      // 20.6 MB
    size_t off = (size_t)NCHUNK * NCLS * NBINS * 4;
    unsigned long long* part2 = (unsigned long long*)(ws + off); // 1.29 MB
    off += (size_t)NGRP * NCLS * NBINS * 8;
    double* losses = (double*)(ws + off);                        // 168 B

    k_fused<<<NCHUNK, 1024, 0, stream>>>((const iv4*)label, (const fv4*)pred, part);
    dim3 mgrid((NCLS * NBINS + 255) / 256, NGRP);
    k_merge<<<mgrid, 256, 0, stream>>>(part, part2);
    k_scan<<<NCLS, 1024, 0, stream>>>(part2, losses);
    k_final<<<1, 64, 0, stream>>>(losses, out);
}